// Round 5
// baseline (188.036 us; speedup 1.0000x reference)
//
#include <hip/hip_runtime.h>
#include <math.h>

#define EMB_DIM 512
#define N_Q 8
#define GAMMA_F 12.0f

typedef float f32x4 __attribute__((ext_vector_type(4)));

// ---------------------------------------------------------------------------
// Single fused kernel. Wave owns (entity stream, query-half).
//
// Prologue: each wave rotates ITS 4 queries directly into registers
//   (24 coalesced f32x4 loads + 32 __sincosf per lane, ~0.5 us total)
//   -- no pre-kernel, no workspace, one launch.
// Main loop: 4 queries in regs (64 VGPR), 3 named entity buffers =
//   2-deep prefetch, ~145 VGPR -> 3 waves/SIMD (12 waves/CU, ~96 KB
//   in flight/CU vs ~12 KB Little's-law minimum at 7 TB/s).
// Wave pairs (2k, 2k+1) share an entity row -> second read L1-hits;
//   HBM traffic stays the mandatory 123 MB.
// No LDS, no barriers; 2-stage transposing butterfly + power sums ->
//   lanes 0..3 store the 4 query scores for this entity.
// ---------------------------------------------------------------------------

// load entity row EIDX (clamped) into 4 named f32x4 regs
#define LOADE(R0, R1, I0, I1, EIDX)                                   \
    do {                                                              \
        int _ec = ((EIDX) < N) ? (EIDX) : 0;                          \
        const float* _p = eemb + (size_t)_ec * (2 * EMB_DIM);         \
        R0 = *(const f32x4*)(_p + o0);                                \
        R1 = *(const f32x4*)(_p + o1);                                \
        I0 = *(const f32x4*)(_p + EMB_DIM + o0);                      \
        I1 = *(const f32x4*)(_p + EMB_DIM + o1);                      \
    } while (0)

// score 4 queries against entity row in (R0,R1,I0,I1); store if in range
#define SCORE(R0, R1, I0, I1, EIDX)                                   \
    do {                                                              \
        float s_[4];                                                  \
        _Pragma("unroll")                                             \
        for (int k = 0; k < 4; ++k) {                                 \
            f32x4 dx = qr0[k] - R0;                                   \
            f32x4 dy = qi0[k] - I0;                                   \
            f32x4 d2 = dx * dx + dy * dy;                             \
            f32x4 ra;                                                 \
            ra.x = __builtin_amdgcn_sqrtf(d2.x);                      \
            ra.y = __builtin_amdgcn_sqrtf(d2.y);                      \
            ra.z = __builtin_amdgcn_sqrtf(d2.z);                      \
            ra.w = __builtin_amdgcn_sqrtf(d2.w);                      \
            dx = qr1[k] - R1;                                         \
            dy = qi1[k] - I1;                                         \
            d2 = dx * dx + dy * dy;                                   \
            f32x4 rb;                                                 \
            rb.x = __builtin_amdgcn_sqrtf(d2.x);                      \
            rb.y = __builtin_amdgcn_sqrtf(d2.y);                      \
            rb.z = __builtin_amdgcn_sqrtf(d2.z);                      \
            rb.w = __builtin_amdgcn_sqrtf(d2.w);                      \
            f32x4 a = ra + rb;                                        \
            s_[k] = (a.x + a.y) + (a.z + a.w);                        \
        }                                                             \
        const bool p1 = lane & 1;                                     \
        float x_, z_, u0, u1;                                         \
        x_ = p1 ? s_[1] : s_[0]; z_ = p1 ? s_[0] : s_[1];             \
        u0 = x_ + __shfl_xor(z_, 1);                                  \
        x_ = p1 ? s_[3] : s_[2]; z_ = p1 ? s_[2] : s_[3];             \
        u1 = x_ + __shfl_xor(z_, 1);                                  \
        const bool p2 = lane & 2;                                     \
        x_ = p2 ? u1 : u0; z_ = p2 ? u0 : u1;                         \
        float u = x_ + __shfl_xor(z_, 2);                             \
        u += __shfl_xor(u, 4);                                        \
        u += __shfl_xor(u, 8);                                        \
        u += __shfl_xor(u, 16);                                       \
        u += __shfl_xor(u, 32);                                       \
        if (lane < 4 && (EIDX) < N)                                   \
            out[(size_t)(qh * 4 + lane) * N + (EIDX)] = GAMMA_F - u;  \
    } while (0)

__global__ __launch_bounds__(256, 3) void rotate_score_kernel(
    const int* __restrict__ all_h,
    const int* __restrict__ all_r,
    const float* __restrict__ eemb,
    const float* __restrict__ remb,
    float* __restrict__ out,
    int N)
{
    const int lane  = threadIdx.x & 63;
    const int wid   = threadIdx.x >> 6;
    const int gwave = blockIdx.x * 4 + wid;
    const int W     = gridDim.x * 4;      // 3072 waves
    const int qh    = gwave & 1;          // query half: queries qh*4 .. qh*4+3
    const int e0    = gwave >> 1;         // first entity, in [0, estep)
    const int estep = W >> 1;             // 1536

    const int o0 = 4 * lane;              // dims [o0, o0+4)
    const int o1 = 256 + 4 * lane;        // dims [o1, o1+4)

    // ---- fused query rotation: this wave's 4 queries into registers ----
    f32x4 qr0[4], qr1[4], qi0[4], qi1[4];
    {
        const float SCALE = (float)(M_PI * (double)EMB_DIM / 14.0);
        #pragma unroll
        for (int k = 0; k < 4; ++k) {
            int q = qh * 4 + k;
            int h = all_h[q];                 // wave-uniform scalar loads
            int r = all_r[q];
            const float* hp = eemb + (size_t)h * (2 * EMB_DIM);
            const float* rp = remb + (size_t)r * EMB_DIM;
            f32x4 reh0 = *(const f32x4*)(hp + o0);
            f32x4 reh1 = *(const f32x4*)(hp + o1);
            f32x4 imh0 = *(const f32x4*)(hp + EMB_DIM + o0);
            f32x4 imh1 = *(const f32x4*)(hp + EMB_DIM + o1);
            f32x4 ph0  = *(const f32x4*)(rp + o0);
            f32x4 ph1  = *(const f32x4*)(rp + o1);
            f32x4 s0, c0, s1, c1;
            #pragma unroll
            for (int j = 0; j < 4; ++j) {
                float s, c;
                __sincosf(ph0[j] * SCALE, &s, &c);
                s0[j] = s; c0[j] = c;
                __sincosf(ph1[j] * SCALE, &s, &c);
                s1[j] = s; c1[j] = c;
            }
            qr0[k] = reh0 * c0 - imh0 * s0;   // re_e fragment
            qr1[k] = reh1 * c1 - imh1 * s1;
            qi0[k] = reh0 * s0 + imh0 * c0;   // im_e fragment
            qi1[k] = reh1 * s1 + imh1 * c1;
        }
    }

    f32x4 Ar0, Ar1, Ai0, Ai1;
    f32x4 Br0, Br1, Bi0, Bi1;
    f32x4 Cr0, Cr1, Ci0, Ci1;

    const int itmax = (N + estep - 1) / estep;   // uniform (e0 < estep)
    int e = e0;
    LOADE(Ar0, Ar1, Ai0, Ai1, e);
    LOADE(Br0, Br1, Bi0, Bi1, e + estep);

    int it = 0;
    for (; it + 3 <= itmax; it += 3) {
        LOADE(Cr0, Cr1, Ci0, Ci1, e + 2 * estep);
        SCORE(Ar0, Ar1, Ai0, Ai1, e);
        e += estep;
        LOADE(Ar0, Ar1, Ai0, Ai1, e + 2 * estep);
        SCORE(Br0, Br1, Bi0, Bi1, e);
        e += estep;
        LOADE(Br0, Br1, Bi0, Bi1, e + 2 * estep);
        SCORE(Cr0, Cr1, Ci0, Ci1, e);
        e += estep;
    }
    if (it < itmax) {
        SCORE(Ar0, Ar1, Ai0, Ai1, e);
        e += estep;
        ++it;
    }
    if (it < itmax) {
        SCORE(Br0, Br1, Bi0, Bi1, e);
    }
}

extern "C" void kernel_launch(void* const* d_in, const int* in_sizes, int n_in,
                              void* d_out, int out_size, void* d_ws, size_t ws_size,
                              hipStream_t stream) {
    const int*   all_h = (const int*)d_in[0];
    const int*   all_r = (const int*)d_in[1];
    const float* eemb  = (const float*)d_in[2];
    const float* remb  = (const float*)d_in[3];
    float* out = (float*)d_out;

    int N = in_sizes[2] / (2 * EMB_DIM);   // 30000

    // single launch: 768 blocks = 3/CU at <=168 VGPR; 3072 waves,
    // 2 per entity stream (query halves share the row via L1).
    rotate_score_kernel<<<768, 256, 0, stream>>>(all_h, all_r, eemb, remb, out, N);
}